// Round 13
// baseline (156.903 us; speedup 1.0000x reference)
//
#include <hip/hip_runtime.h>
#include <stdint.h>
#include <stddef.h>

// GA3 conv2d == one dense 3x3 conv with sign-permuted weights:
//   out[b, c*8+m, h, w] = bias_eff[c*8+m]
//     + sum_{cin,k,kh,kw} s(m,k) * W[j(m,k),c,cin,kh,kw] * x[b, cin*8+k, h+kh-1, w+kw-1]
// bf16 MFMA implicit GEMM over 9 taps (K=128 each).
// R10: MFMA shape 16x16x32 -> 32x32x16. Measured invariance (R1=R6=R9 ~48-49us
// across all B-sourcing/barrier schedules) localized the cost to the per-iter
// read:compute ratio: 8 ds_read_b128 covered only 78cyc of MFMA (10 cyc/read).
// Now 4 reads cover 155cyc (39 cyc/read, 4x) -- same LDS bytes, same FLOPs,
// same 64-f32 acc. Orientation: A=weights(row=oc), B=pixels(col=px) so stores
// stay w-contiguous 64B segments. Everything else byte-identical to R9.

typedef __attribute__((ext_vector_type(8))) short short8;    // 8 x bf16 (4 VGPRs)
typedef __attribute__((ext_vector_type(16))) float f32x16;   // 32x32 MFMA accumulator

#define GLD_LDS16(gsrc, ldst) __builtin_amdgcn_global_load_lds( \
    (const __attribute__((address_space(1))) void*)(gsrc),      \
    (__attribute__((address_space(3))) void*)(ldst), 16, 0, 0)

// j(m,k) and s(m,k): unique j with S[m,j,k]!=0, transcribed from _TERMS.
__device__ __constant__ int c_J[64] = {
  0,1,2,3,4,5,6,7,
  1,0,4,6,2,7,3,5,
  2,4,0,5,1,3,7,6,
  3,6,5,0,7,2,1,4,
  4,2,1,7,0,6,5,3,
  5,7,3,2,6,0,4,1,
  6,3,7,1,5,4,0,2,
  7,5,6,4,3,1,2,0
};
__device__ __constant__ float c_Sg[64] = {
  1,1,1,1,-1,-1,-1,-1,
  1,1,-1,-1,1,-1,1,-1,
  1,1,1,-1,-1,1,1,1,
  1,1,1,1,-1,-1,-1,-1,
  1,1,-1,1,1,1,-1,1,
  1,1,1,-1,-1,1,1,1,
  1,1,-1,-1,1,-1,1,-1,
  1,1,-1,1,1,1,-1,1
};

__device__ inline unsigned short f2bf(float f) {  // RNE float->bf16
  unsigned int u = __float_as_uint(f);
  u += 0x7FFFu + ((u >> 16) & 1u);
  return (unsigned short)(u >> 16);
}

// ---------------- Prep A: x [8][128][128][128] f32 NCHW -> xt [8][130][130][128] bf16 NHWC
// (padded). One block per (h, b): full 128-w row, all 128 ic. float4 reads,
// LDS [ic][stride 129] (odd stride: both phases 2-way = free), uint2 writes.
// Border zeroing folded in: col 0/129 every block; rows 0/129 in h==0/127 blocks.
__global__ __launch_bounds__(256) void xpose_kernel(const float* __restrict__ x,
                                                    unsigned short* __restrict__ xt) {
  __shared__ unsigned short t[128 * 129];   // 33,024 B
  const int h   = blockIdx.x;       // 0..127
  const int b   = blockIdx.y;       // 0..7
  const int tid = threadIdx.x;
  // Phase 1: global float4 -> bf16 -> LDS [ic][w]
  #pragma unroll
  for (int i = 0; i < 16; ++i) {
    int idx = tid + i * 256;        // 0..4095 = 128 ic * 32 w-quads
    int ic = idx >> 5, wq = idx & 31;
    const float4 v = *(const float4*)(x + ((size_t)(b * 128 + ic) * 128 + h) * 128 + 4 * wq);
    unsigned short* d = t + ic * 129 + 4 * wq;
    d[0] = f2bf(v.x); d[1] = f2bf(v.y); d[2] = f2bf(v.z); d[3] = f2bf(v.w);
  }
  // Border: cols 0 and 129 of this row (h+1)
  if (tid < 128) {
    int c = tid >> 6, u = tid & 63;
    *(unsigned int*)(xt + ((size_t)(b * 130 + h + 1) * 130 + c * 129) * 128 + 2 * u) = 0u;
  }
  // Border: rows 0 / 129 (only the h==0 / h==127 blocks)
  if (h == 0 || h == 127) {
    int row = (h == 0) ? 0 : 129;
    for (int i = 0; i < 33; ++i) {
      int idx = tid + i * 256;      // 130 px * 64 uints = 8320
      if (idx < 8320) {
        int w = idx >> 6, u = idx & 63;
        *(unsigned int*)(xt + ((size_t)(b * 130 + row) * 130 + w) * 128 + 2 * u) = 0u;
      }
    }
  }
  __syncthreads();
  // Phase 2: LDS -> global, ic-contiguous uint2 (4 ic per lane per iter)
  #pragma unroll
  for (int i = 0; i < 16; ++i) {
    int idx = tid + i * 256;        // 0..4095 = 128 w * 32 ic-quads
    int w = idx >> 5, p4 = idx & 31;
    unsigned int s0 = t[(4 * p4 + 0) * 129 + w];
    unsigned int s1 = t[(4 * p4 + 1) * 129 + w];
    unsigned int s2 = t[(4 * p4 + 2) * 129 + w];
    unsigned int s3 = t[(4 * p4 + 3) * 129 + w];
    uint2 o; o.x = s0 | (s1 << 16); o.y = s2 | (s3 << 16);
    *(uint2*)(xt + ((size_t)(b * 130 + h + 1) * 130 + (w + 1)) * 128 + 4 * p4) = o;
  }
}

// ---------------- Prep B: vt[t][ks32][ocb][lane][8] bf16 — tap t's 32KB block is a flat
// [ks32][ocb][512-short] region; conv stages it in two 16KB halves:
// oc = ocb*16 + (lane&15), ic = ks32*32 + quad*8 + e.  Also bias_eff[128] f32.
__global__ __launch_bounds__(256) void prep_kernel(const float* __restrict__ W,
                                                   const float* __restrict__ bias,
                                                   unsigned short* __restrict__ vt,
                                                   float* __restrict__ beff) {
  int gid = blockIdx.x * 256 + threadIdx.x;   // 9*128*128 = 147456 threads exactly
  int t   = gid >> 14;
  int rem = gid & 16383;
  int oc  = rem >> 7;
  int ic  = rem & 127;
  int m = oc & 7, cout = oc >> 3;
  int k = ic & 7, cin = ic >> 3;
  int j = c_J[m * 8 + k];
  float s = c_Sg[m * 8 + k];
  float val = s * W[((j * 16 + cout) * 16 + cin) * 9 + t];
  int ks = ic >> 5, quad = (ic >> 3) & 3, e = ic & 7;
  int ocb = oc >> 4, l15 = oc & 15;
  vt[(size_t)((t * 4 + ks) * 8 + ocb) * 512 + (quad * 16 + l15) * 8 + e] = f2bf(val);
  if (gid < 128) {
    int m2 = gid & 7, cout2 = gid >> 3;
    float acc = 0.f;
    #pragma unroll
    for (int kk = 0; kk < 8; ++kk)
      acc += c_Sg[m2 * 8 + kk] * bias[c_J[m2 * 8 + kk] * 16 + cout2];
    beff[gid] = acc;
  }
}

// ---------------- Main: tap-decomposed implicit GEMM, bf16 MFMA 32x32x16 ----------------
// Block: 256 thr = 4 waves. Tile: 8 rows x 16 cols of output pixels x all 128 oc.
// Wave (wm,wn): 2 m-tiles (32px = 2h x 16w each) x 2 n-tiles (32 oc each); acc 2x2xf32x16.
// MFMA orientation: D = A(weights) x B(pixels): D col = lane&31 = px (w-contiguous
// stores), D row = oc = (reg&3) + 4*(lane>>5) + 8*(reg>>2)  [m74/m101 layout].
// A-frag: lane: oc = ntile*32 + (lane&31), ic = ks16*16 + (lane>>5)*8 + e (from lds_w).
// B-frag: lane: px = lane&31 -> (h = 2*mtile + (lane>>4&1), w = lane&15),
//         ic = ks16*16 + (lane>>5)*8 + e (from swizzled lds_x).
// Per ks16: 4 ds_read_b128 -> 4 MFMA (155 cyc/SIMD cover vs 78 before).
// lds_x XOR-swizzle + staging + lds_w half-tap double-buffer: identical to R9.
__global__ __launch_bounds__(256) void conv_kernel(const unsigned short* __restrict__ xt,
                                                   const unsigned short* __restrict__ vt,
                                                   const float* __restrict__ beff,
                                                   float* __restrict__ out) {
  __shared__ __align__(16) unsigned short lds_x[10 * 18 * 128]; // halo [hh][ww][ic], 45 KiB
  __shared__ __align__(16) unsigned short lds_w[2][64 * 128];   // two half-tap buffers, 16 KiB each
  const int tid  = threadIdx.x;
  const int bx   = blockIdx.x;    // 0..7   w tile (16)
  const int by   = blockIdx.y;    // 0..15  h tile (8)
  const int b    = blockIdx.z;    // 0..7
  const int lane = tid & 63;
  const int wave = tid >> 6;
  const int wm   = wave >> 1;     // 0..1  m-half (h rows 4*wm..4*wm+3)
  const int wn   = wave & 1;      // 0..1  n-half (oc 64*wn..64*wn+63)
  const int l15  = lane & 15;
  const int lh   = (lane >> 4) & 1;   // h-bit within a 32-px tile / ocb-bit
  const int lk   = lane >> 5;         // k-group bit

#define STAGE_HALF(DST, SRCOFF)                                         \
  {                                                                     \
    const char* s_ = (const char*)vt + (SRCOFF);                        \
    _Pragma("unroll")                                                   \
    for (int i_ = 0; i_ < 4; ++i_) {                                    \
      int c_ = (tid + i_ * 256) * 16;                                   \
      GLD_LDS16(s_ + c_, (char*)(DST) + c_);                            \
    }                                                                   \
  }

  // Per half (16KB = [ks32_loc 0..1][ocb 0..7][512 shorts]); l16 = ks16 within half.
#define HALF_COMPUTE(WBUF, KS16BASE)                                    \
  {                                                                     \
    _Pragma("unroll")                                                   \
    for (int l16 = 0; l16 < 4; ++l16) {                                 \
      const int ks16 = (KS16BASE) + l16;                                \
      short8 wf[2], xf[2];                                              \
      _Pragma("unroll")                                                 \
      for (int nt = 0; nt < 2; ++nt) {                                  \
        int ocb = (wn * 2 + nt) * 2 + lh;                               \
        int qk  = (l16 & 1) * 2 + lk;                                   \
        wf[nt] = *(const short8*)((WBUF) + ((l16 >> 1) * 8 + ocb) * 512 \
                                         + (qk * 16 + l15) * 8);        \
      }                                                                 \
      _Pragma("unroll")                                                 \
      for (int mt = 0; mt < 2; ++mt) {                                  \
        int row = rowb[mt];                                             \
        int off = row * 256 + ((ks16 * 32 + (lk << 4)) ^ ((row & 7) << 4)); \
        xf[mt] = *(const short8*)((const char*)lds_x + off);            \
      }                                                                 \
      _Pragma("unroll")                                                 \
      for (int mt = 0; mt < 2; ++mt)                                    \
        _Pragma("unroll")                                               \
        for (int nt = 0; nt < 2; ++nt)                                  \
          acc[mt][nt] = __builtin_amdgcn_mfma_f32_32x32x16_bf16(wf[nt], xf[mt], acc[mt][nt], 0, 0, 0); \
    }                                                                   \
  }

  // Prologue: issue tap-0 ks16{0..3} into W0 (async, rides under A staging).
  STAGE_HALF(lds_w[0], 0);

  // Stage x halo tile (rows by*8..+9, cols bx*16..+17, 128 ic) = 2880 x 16B chunks,
  // swizzled on the write side.
  {
    const unsigned short* xb = xt + ((size_t)(b * 130 + by * 8) * 130 + bx * 16) * 128;
    #pragma unroll
    for (int i = 0; i < 11; ++i) {
      int c  = tid + i * 256;
      int hh = c / 288;            // 288 chunks per halo row (18*128*2B/16B)
      int r  = c - hh * 288;
      uint4 v = *((const uint4*)(xb + (size_t)hh * (130 * 128)) + r);
      ((uint4*)lds_x)[c ^ ((c >> 4) & 7)] = v;
    }
    if (tid < 64) {                // tail: chunks 2816..2879
      int c  = tid + 2816;
      int hh = c / 288;
      int r  = c - hh * 288;
      uint4 v = *((const uint4*)(xb + (size_t)hh * (130 * 128)) + r);
      ((uint4*)lds_x)[c ^ ((c >> 4) & 7)] = v;
    }
  }
  asm volatile("s_waitcnt vmcnt(0)" ::: "memory");
  __syncthreads();                 // x tile AND W0 (tap0 first half) ready

  f32x16 acc[2][2];
  #pragma unroll
  for (int mt = 0; mt < 2; ++mt)
    #pragma unroll
    for (int nt = 0; nt < 2; ++nt)
      acc[mt][nt] = f32x16{0.f,0.f,0.f,0.f,0.f,0.f,0.f,0.f,0.f,0.f,0.f,0.f,0.f,0.f,0.f,0.f};

  #pragma unroll
  for (int t = 0; t < 9; ++t) {
    const int dh = t / 3, dw = t % 3;
    int rowb[2];
    #pragma unroll
    for (int mt = 0; mt < 2; ++mt)   // B-frag pixel row: h = (wm*2+mt)*2 + lh, + dh halo
      rowb[mt] = ((wm * 2 + mt) * 2 + lh + dh) * 18 + l15 + dw;

    STAGE_HALF(lds_w[1], (size_t)t * 32768 + 16384);   // ks16 4..7 of tap t, hides under:
    HALF_COMPUTE(lds_w[0], 0)                          // 16 MFMA on ks16 0..3
    asm volatile("s_waitcnt vmcnt(0)" ::: "memory");
    __syncthreads();                                   // W1 ready; W0 free

    if (t < 8) STAGE_HALF(lds_w[0], (size_t)(t + 1) * 32768);  // next tap 1st half
    HALF_COMPUTE(lds_w[1], 4)                          // 16 MFMA on ks16 4..7
    if (t < 8) {
      asm volatile("s_waitcnt vmcnt(0)" ::: "memory");
      __syncthreads();                                 // W0 ready; W1 free
    }
  }

  // Epilogue: D col = lane&31 = px (w-contiguous across lanes 0-15),
  // D row = oc = (r&3) + 4*lk + 8*(r>>2). Scalar f32 stores, 64B segments.
  const int h0 = by * 8, w0 = bx * 16;
  #pragma unroll
  for (int mt = 0; mt < 2; ++mt) {
    int h = h0 + (wm * 2 + mt) * 2 + lh;
    int w = w0 + l15;
    #pragma unroll
    for (int nt = 0; nt < 2; ++nt) {
      f32x16 v = acc[mt][nt];
      #pragma unroll
      for (int r = 0; r < 16; ++r) {
        int oc = (wn * 2 + nt) * 32 + (r & 3) + (lk << 2) + ((r >> 2) << 3);
        out[((size_t)(b * 128 + oc) * 128 + h) * 128 + w] = v[r] + beff[oc];
      }
    }
  }
#undef STAGE_HALF
#undef HALF_COMPUTE
}

extern "C" void kernel_launch(void* const* d_in, const int* in_sizes, int n_in,
                              void* d_out, int out_size, void* d_ws, size_t ws_size,
                              hipStream_t stream) {
  (void)in_sizes; (void)n_in; (void)out_size; (void)ws_size;
  const float* x    = (const float*)d_in[0];   // [8][128][128][128]
  const float* W    = (const float*)d_in[1];   // [8][16][16][3][3]
  const float* bias = (const float*)d_in[2];   // [8][16]
  float* out = (float*)d_out;                  // [8][128][128][128]

  const size_t XT_BYTES = (size_t)8 * 130 * 130 * 128 * 2;   // 34,611,200
  const size_t VT_BYTES = (size_t)9 * 4 * 8 * 512 * 2;       //    294,912
  unsigned short* xt = (unsigned short*)d_ws;
  unsigned short* vt = (unsigned short*)((char*)d_ws + XT_BYTES);
  float* beff = (float*)((char*)d_ws + XT_BYTES + VT_BYTES);

  prep_kernel<<<dim3(576), 256, 0, stream>>>(W, bias, vt, beff);       // vt + beff
  xpose_kernel<<<dim3(128, 8), 256, 0, stream>>>(x, xt);               // incl. border zero
  conv_kernel<<<dim3(8, 16, 8), 256, 0, stream>>>(xt, vt, beff, out);
}